// Round 14
// baseline (90.324 us; speedup 1.0000x reference)
//
#include <hip/hip_runtime.h>
#include <stdint.h>

// MHABlock: b=8, c=128, heads=8, d=16, spatial 32x32 (p=1024).
// Softmax over last spatial axis only -> independent 32-key blocks.
// R14: R13's 3-stage pipelined attn + packed-f32 sum tree re-applied (R9-
// proven), proj split to 768 blocks (3/CU even makespan, was 384 -> 2-deep
// on half the CUs). Deferred normalization; distance-2/3 operand prefetch.
// S^T = K*Q^T via mfma_32x32x16 (K=16 exact); V stored y-bits-2,3-swapped so
// PV B-frags are sequential in-lane packs of the exp'd scores.

typedef __bf16 bf16x8 __attribute__((ext_vector_type(8)));
typedef float f32x16 __attribute__((ext_vector_type(16)));
typedef float f32x2 __attribute__((ext_vector_type(2)));

// ws layout (units: shorts): Q | K | V, 1M shorts each
#define QOFF  0u
#define KOFF  (1u << 20)
#define VOFF  (2u << 20)

static __device__ __forceinline__ unsigned short f2bf(float f) {
  union { float f; uint32_t u; } v; v.f = f;
  uint32_t r = (v.u + 0x7FFFu + ((v.u >> 16) & 1u)) >> 16;  // RNE
  return (unsigned short)r;
}
static __device__ __forceinline__ uint32_t pkrne(float lo, float hi) {
  return (uint32_t)f2bf(lo) | ((uint32_t)f2bf(hi) << 16);
}
static __device__ __forceinline__ uint32_t pktrunc(float lo, float hi) {
  return (__builtin_bit_cast(uint32_t, hi) & 0xffff0000u) |
         (__builtin_bit_cast(uint32_t, lo) >> 16);
}
static __device__ __forceinline__ float fexp2(float x) {
  float r;
  asm("v_exp_f32 %0, %1" : "=v"(r) : "v"(x));  // non-volatile: schedulable
  return r;
}
static __device__ __forceinline__ f32x16 zero16() {
  f32x16 z;
#pragma unroll
  for (int i = 0; i < 16; ++i) z[i] = 0.f;
  return z;
}
// swap bits 2,3 (V spatial permutation within each 32-block)
static __device__ __forceinline__ int perm23(int p) {
  return (p & ~12) | ((p & 4) << 1) | ((p & 8) >> 1);
}
static __device__ __forceinline__ bf16x8 pack8(float f0, float f1, float f2,
                                               float f3, float f4, float f5,
                                               float f6, float f7) {
  uint4 u = make_uint4(pkrne(f0, f1), pkrne(f2, f3), pkrne(f4, f5), pkrne(f6, f7));
  return __builtin_bit_cast(bf16x8, u);
}

// ---------------------------------------------------------------------------
// proj (MFMA, fused fp32->bf16): D[out 32][p 32], K=128.
// grid = b*96 + mat*32 + ptile (768 blocks = 3/CU even), block = 256
// (4 waves; wave = one 32-out m-tile x one 32-p n-tile).
// Q/K stored [bn][p][d] (Q scaled by 0.25*log2e); V stored [bn][d][perm23(p)].
// ---------------------------------------------------------------------------
__global__ __launch_bounds__(256) void proj_kernel(
    const float* __restrict__ x, const float* __restrict__ wq,
    const float* __restrict__ wk, const float* __restrict__ wv,
    unsigned short* __restrict__ ws) {
  int bid = blockIdx.x;
  int ptile = bid & 31;
  int mat = (bid >> 5) % 3;
  int b = bid / 96;
  int t = threadIdx.x;
  int wave = t >> 6, lane = t & 63;
  int h = lane >> 5, c = lane & 31;
  int out0 = wave * 32;

  const float* w = (mat == 0) ? wq : ((mat == 1) ? wk : wv);
  const float* wrow = w + (size_t)(out0 + c) * 128 + h * 8;      // A: W[out0+c][k]
  const float* xcol = x + (size_t)b * 131072 + ptile * 32 + c;   // B: x[ch][p]

  f32x16 acc = zero16();
#pragma unroll
  for (int kt = 0; kt < 8; ++kt) {
    int ch0 = kt * 16 + h * 8;
    float4 wa = *(const float4*)(wrow + kt * 16);
    float4 wb4 = *(const float4*)(wrow + kt * 16 + 4);
    float xb[8];
#pragma unroll
    for (int j = 0; j < 8; ++j) xb[j] = xcol[(size_t)(ch0 + j) * 1024];
    bf16x8 af = pack8(wa.x, wa.y, wa.z, wa.w, wb4.x, wb4.y, wb4.z, wb4.w);
    bf16x8 bf = pack8(xb[0], xb[1], xb[2], xb[3], xb[4], xb[5], xb[6], xb[7]);
    acc = __builtin_amdgcn_mfma_f32_32x32x16_bf16(af, bf, acc, 0, 0, 0);
  }

  int p = ptile * 32 + c;
  if (mat < 2) {
    // Q: fold softmax scale d^-0.5 * log2(e) (attn uses exp2)
    float s = (mat == 0) ? 0.36067376022224085f : 1.0f;
    unsigned short* dst = ws + ((mat == 0) ? QOFF : KOFF);
#pragma unroll
    for (int rg = 0; rg < 4; ++rg) {
      int bn = b * 8 + wave * 2 + (rg >> 1);
      int dbase = ((rg & 1) ? 8 : 0) + 4 * h;
      uint32_t lo = pkrne(acc[rg * 4 + 0] * s, acc[rg * 4 + 1] * s);
      uint32_t hi = pkrne(acc[rg * 4 + 2] * s, acc[rg * 4 + 3] * s);
      *(uint2*)(dst + (size_t)bn * 16384 + (size_t)p * 16 + dbase) =
          make_uint2(lo, hi);
    }
  } else {
    int pp = perm23(p);
#pragma unroll
    for (int r = 0; r < 16; ++r) {
      int moff = (r & 3) + 8 * (r >> 2) + 4 * h;
      int head = (out0 + moff) >> 4;
      int d = moff & 15;
      ws[VOFF + (size_t)(b * 8 + head) * 16384 + (size_t)d * 1024 + pp] =
          f2bf(acc[r]);
    }
  }
}

// ---------------------------------------------------------------------------
// attn: grid = bn*8+qc (512), block = 256 (4 waves), 32 q/wave, 32 x-blocks.
// No LDS, no barriers, direct stores. 3-stage pipeline: iter x issues S(x+1),
// runs exp/sum (packed f32x2) for x, and pack+PV+fold for x-1.
// ---------------------------------------------------------------------------
__global__ __launch_bounds__(256) void attn_kernel(
    const unsigned short* __restrict__ ws, float* __restrict__ out) {
  int bid = blockIdx.x;
  int qc = bid & 7, bn = bid >> 3;
  const unsigned short* Qg = ws + QOFF + (size_t)bn * 16384;
  const unsigned short* Kg = ws + KOFF + (size_t)bn * 16384;
  const unsigned short* Vg = ws + VOFF + (size_t)bn * 16384;

  int t = threadIdx.x;
  int wave = t >> 6, lane = t & 63;
  int h = lane >> 5, c = lane & 31;
  int q0 = qc * 128 + wave * 32;

  // Q B-frag: B[k=d=8h+j][n=q=c], K=16 exact
  bf16x8 qb = __builtin_bit_cast(
      bf16x8, *(const uint4*)(Qg + (size_t)(q0 + c) * 16 + h * 8));

  // K A-frag: lane reads K[x*32 + c][8h..8h+7]  (coalesced 16B/lane)
  const unsigned short* kbase = Kg + (size_t)c * 16 + h * 8;
  // V A-frag: lane reads V'[c&15][x*32 + 8h..]
  const unsigned short* vbase = Vg + (size_t)(c & 15) * 1024 + h * 8;

  float acc[8];
#pragma unroll
  for (int r = 0; r < 8; ++r) acc[r] = 0.f;

  // ---- prologue ----
  bf16x8 va0_p = __builtin_bit_cast(bf16x8, *(const uint4*)(vbase));
  bf16x8 va1_p = __builtin_bit_cast(bf16x8, *(const uint4*)(vbase + 16));
  uint4 v0_c = *(const uint4*)(vbase + 32);        // V(1)
  uint4 v1_c = *(const uint4*)(vbase + 48);
  uint4 v0_n = *(const uint4*)(vbase + 64);        // V(2)
  uint4 v1_n = *(const uint4*)(vbase + 80);

  f32x16 sv_cur;
  {
    uint4 kf0 = *(const uint4*)(kbase);
    f32x16 sv0 = __builtin_amdgcn_mfma_f32_32x32x16_bf16(
        __builtin_bit_cast(bf16x8, kf0), qb, zero16(), 0, 0, 0);
    uint4 kf1 = *(const uint4*)(kbase + 512);
    sv_cur = __builtin_amdgcn_mfma_f32_32x32x16_bf16(   // S(1)
        __builtin_bit_cast(bf16x8, kf1), qb, zero16(), 0, 0, 0);

    // stage2(0): packed exp/sum
    f32x2 e_prev[8];
#pragma unroll
    for (int j = 0; j < 8; ++j) {
      e_prev[j].x = fexp2(sv0[2 * j]);
      e_prev[j].y = fexp2(sv0[2 * j + 1]);
    }
    f32x2 t0 = (e_prev[0] + e_prev[1]) + (e_prev[2] + e_prev[3]);
    f32x2 t1 = (e_prev[4] + e_prev[5]) + (e_prev[6] + e_prev[7]);
    f32x2 ts = t0 + t1;
    float sum = ts.x + ts.y;
    sum += __shfl_xor(sum, 32);
    float rs_prev = __builtin_amdgcn_rcpf(sum);

    uint4 kf_a = *(const uint4*)(kbase + 2 * 512);   // K(2)
    uint4 kf_b = *(const uint4*)(kbase + 3 * 512);   // K(3)

    // ---- main loop: x = 1..31 ----
#pragma unroll 2
    for (int x = 1; x < 32; ++x) {
      // stage1: issue S(x+1)
      f32x16 sv_next = __builtin_amdgcn_mfma_f32_32x32x16_bf16(
          __builtin_bit_cast(bf16x8, kf_a), qb, zero16(), 0, 0, 0);
      kf_a = kf_b;
      int x3 = (x > 28) ? 31 : (x + 3);
      kf_b = *(const uint4*)(kbase + (size_t)x3 * 512);

      // stage3 for x-1: pack e_prev -> PV (two independent C=0 tiles) -> fold
      uint32_t pk[8];
#pragma unroll
      for (int j = 0; j < 8; ++j) pk[j] = pktrunc(e_prev[j].x, e_prev[j].y);
      bf16x8 p0 = __builtin_bit_cast(bf16x8, make_uint4(pk[0], pk[1], pk[2], pk[3]));
      bf16x8 p1 = __builtin_bit_cast(bf16x8, make_uint4(pk[4], pk[5], pk[6], pk[7]));
      f32x16 pv0 = __builtin_amdgcn_mfma_f32_32x32x16_bf16(va0_p, p0, zero16(), 0, 0, 0);
      f32x16 pv1 = __builtin_amdgcn_mfma_f32_32x32x16_bf16(va1_p, p1, zero16(), 0, 0, 0);
#pragma unroll
      for (int r = 0; r < 8; ++r) acc[r] = fmaf(rs_prev, pv0[r] + pv1[r], acc[r]);

      // stage2 for x: packed exp/sum on sv_cur (computed at iter x-1)
      f32x2 e_cur[8];
#pragma unroll
      for (int j = 0; j < 8; ++j) {
        e_cur[j].x = fexp2(sv_cur[2 * j]);
        e_cur[j].y = fexp2(sv_cur[2 * j + 1]);
      }
      f32x2 u0 = (e_cur[0] + e_cur[1]) + (e_cur[2] + e_cur[3]);
      f32x2 u1 = (e_cur[4] + e_cur[5]) + (e_cur[6] + e_cur[7]);
      f32x2 us = u0 + u1;
      float su = us.x + us.y;
      su += __shfl_xor(su, 32);
      float rs_cur = __builtin_amdgcn_rcpf(su);

      // rotate V: va_p <- V(x); v_c <- V(x+1); load V(x+2)
      va0_p = __builtin_bit_cast(bf16x8, v0_c);
      va1_p = __builtin_bit_cast(bf16x8, v1_c);
      v0_c = v0_n; v1_c = v1_n;
      int x2 = (x > 29) ? 31 : (x + 2);
      v0_n = *(const uint4*)(vbase + x2 * 32);
      v1_n = *(const uint4*)(vbase + x2 * 32 + 16);

      // rotate pipeline state
      sv_cur = sv_next;
#pragma unroll
      for (int j = 0; j < 8; ++j) e_prev[j] = e_cur[j];
      rs_prev = rs_cur;
    }

    // ---- epilogue: stage3 for x=31 ----
    uint32_t pk[8];
#pragma unroll
    for (int j = 0; j < 8; ++j) pk[j] = pktrunc(e_prev[j].x, e_prev[j].y);
    bf16x8 p0 = __builtin_bit_cast(bf16x8, make_uint4(pk[0], pk[1], pk[2], pk[3]));
    bf16x8 p1 = __builtin_bit_cast(bf16x8, make_uint4(pk[4], pk[5], pk[6], pk[7]));
    f32x16 pv0 = __builtin_amdgcn_mfma_f32_32x32x16_bf16(va0_p, p0, zero16(), 0, 0, 0);
    f32x16 pv1 = __builtin_amdgcn_mfma_f32_32x32x16_bf16(va1_p, p1, zero16(), 0, 0, 0);
#pragma unroll
    for (int r = 0; r < 8; ++r) acc[r] = fmaf(rs_prev, pv0[r] + pv1[r], acc[r]);
  }

  // Epilogue: D rows 0..15 valid (rows 16..31 are duplicate-V garbage)
#pragma unroll
  for (int r = 0; r < 8; ++r) {
    int d = (r & 3) + 8 * (r >> 2) + 4 * h;
    out[(size_t)(bn * 16 + d) * 1024 + q0 + c] = acc[r];
  }
}

// ---------------------------------------------------------------------------
extern "C" void kernel_launch(void* const* d_in, const int* in_sizes, int n_in,
                              void* d_out, int out_size, void* d_ws, size_t ws_size,
                              hipStream_t stream) {
  const float* x  = (const float*)d_in[0];
  const float* wq = (const float*)d_in[1];
  const float* wk = (const float*)d_in[2];
  const float* wv = (const float*)d_in[3];
  unsigned short* ws = (unsigned short*)d_ws;
  float* out = (float*)d_out;

  proj_kernel<<<dim3(768), dim3(256), 0, stream>>>(x, wq, wk, wv, ws);
  attn_kernel<<<dim3(512), dim3(256), 0, stream>>>(ws, out);
}

// Round 15
// 88.601 us; speedup vs baseline: 1.0194x; 1.0194x over previous
//
#include <hip/hip_runtime.h>
#include <stdint.h>

// MHABlock: b=8, c=128, heads=8, d=16, spatial 32x32 (p=1024).
// Softmax over last spatial axis only -> independent 32-key blocks.
// R15 = R13 verbatim (best measured: 88.4us, absmax 0.125). R14's two
// tweaks (packed stage-2 sums, proj 768-block split) regressed: stage-2 is
// off the critical path since R13, so packing it saves nothing; proj split
// doubled W re-reads for a small makespan gain. Reverted.
// 3-stage software-pipelined attn: iter x issues S(x+1), runs exp/sum/rcp
// for x (sv from x-1), and pack+PV+rs-fold for x-1. Deferred normalization;
// distance-2/3 operand prefetch. S^T = K*Q^T via mfma_32x32x16 (K=16 exact);
// V stored y-bits-2,3-swapped so PV B-frags are sequential in-lane packs.

typedef __bf16 bf16x8 __attribute__((ext_vector_type(8)));
typedef float f32x16 __attribute__((ext_vector_type(16)));

// ws layout (units: shorts): Q | K | V, 1M shorts each
#define QOFF  0u
#define KOFF  (1u << 20)
#define VOFF  (2u << 20)

static __device__ __forceinline__ unsigned short f2bf(float f) {
  union { float f; uint32_t u; } v; v.f = f;
  uint32_t r = (v.u + 0x7FFFu + ((v.u >> 16) & 1u)) >> 16;  // RNE
  return (unsigned short)r;
}
static __device__ __forceinline__ uint32_t pkrne(float lo, float hi) {
  return (uint32_t)f2bf(lo) | ((uint32_t)f2bf(hi) << 16);
}
static __device__ __forceinline__ uint32_t pktrunc(float lo, float hi) {
  return (__builtin_bit_cast(uint32_t, hi) & 0xffff0000u) |
         (__builtin_bit_cast(uint32_t, lo) >> 16);
}
static __device__ __forceinline__ float fexp2(float x) {
  float r;
  asm("v_exp_f32 %0, %1" : "=v"(r) : "v"(x));  // non-volatile: schedulable
  return r;
}
static __device__ __forceinline__ f32x16 zero16() {
  f32x16 z;
#pragma unroll
  for (int i = 0; i < 16; ++i) z[i] = 0.f;
  return z;
}
// swap bits 2,3 (V spatial permutation within each 32-block)
static __device__ __forceinline__ int perm23(int p) {
  return (p & ~12) | ((p & 4) << 1) | ((p & 8) >> 1);
}
static __device__ __forceinline__ bf16x8 pack8(float f0, float f1, float f2,
                                               float f3, float f4, float f5,
                                               float f6, float f7) {
  uint4 u = make_uint4(pkrne(f0, f1), pkrne(f2, f3), pkrne(f4, f5), pkrne(f6, f7));
  return __builtin_bit_cast(bf16x8, u);
}

// ---------------------------------------------------------------------------
// proj (MFMA, fused fp32->bf16): D[out 32][p 32], K=128.
// grid = b*48 + mat*16 + ptile (384), block = 256.
// ---------------------------------------------------------------------------
__global__ __launch_bounds__(256) void proj_kernel(
    const float* __restrict__ x, const float* __restrict__ wq,
    const float* __restrict__ wk, const float* __restrict__ wv,
    unsigned short* __restrict__ ws) {
  int bid = blockIdx.x;
  int ptile = bid & 15;
  int mat = (bid >> 4) % 3;
  int b = bid / 48;
  int t = threadIdx.x;
  int wave = t >> 6, lane = t & 63;
  int h = lane >> 5, c = lane & 31;
  int out0 = wave * 32;

  const float* w = (mat == 0) ? wq : ((mat == 1) ? wk : wv);
  const float* wrow = w + (size_t)(out0 + c) * 128 + h * 8;      // A: W[out0+c][k]
  const float* xcol = x + (size_t)b * 131072 + ptile * 64 + c;   // B: x[ch][p]

  f32x16 acc0 = zero16(), acc1 = zero16();
#pragma unroll
  for (int kt = 0; kt < 8; ++kt) {
    int ch0 = kt * 16 + h * 8;
    float4 wa = *(const float4*)(wrow + kt * 16);
    float4 wb4 = *(const float4*)(wrow + kt * 16 + 4);
    float xb0[8], xb1[8];
#pragma unroll
    for (int j = 0; j < 8; ++j) {
      xb0[j] = xcol[(size_t)(ch0 + j) * 1024];
      xb1[j] = xcol[(size_t)(ch0 + j) * 1024 + 32];
    }
    bf16x8 af = pack8(wa.x, wa.y, wa.z, wa.w, wb4.x, wb4.y, wb4.z, wb4.w);
    bf16x8 b0 = pack8(xb0[0], xb0[1], xb0[2], xb0[3], xb0[4], xb0[5], xb0[6], xb0[7]);
    bf16x8 b1 = pack8(xb1[0], xb1[1], xb1[2], xb1[3], xb1[4], xb1[5], xb1[6], xb1[7]);
    acc0 = __builtin_amdgcn_mfma_f32_32x32x16_bf16(af, b0, acc0, 0, 0, 0);
    acc1 = __builtin_amdgcn_mfma_f32_32x32x16_bf16(af, b1, acc1, 0, 0, 0);
  }

  if (mat < 2) {
    // Q: fold softmax scale d^-0.5 * log2(e) (attn uses exp2)
    float s = (mat == 0) ? 0.36067376022224085f : 1.0f;
    unsigned short* dst = ws + ((mat == 0) ? QOFF : KOFF);
#pragma unroll
    for (int nt = 0; nt < 2; ++nt) {
      f32x16 a = nt ? acc1 : acc0;
      int p = ptile * 64 + nt * 32 + c;
#pragma unroll
      for (int rg = 0; rg < 4; ++rg) {
        int bn = b * 8 + wave * 2 + (rg >> 1);
        int dbase = ((rg & 1) ? 8 : 0) + 4 * h;
        uint32_t lo = pkrne(a[rg * 4 + 0] * s, a[rg * 4 + 1] * s);
        uint32_t hi = pkrne(a[rg * 4 + 2] * s, a[rg * 4 + 3] * s);
        *(uint2*)(dst + (size_t)bn * 16384 + (size_t)p * 16 + dbase) =
            make_uint2(lo, hi);
      }
    }
  } else {
#pragma unroll
    for (int nt = 0; nt < 2; ++nt) {
      f32x16 a = nt ? acc1 : acc0;
      int p = ptile * 64 + nt * 32 + c;
      int pp = perm23(p);
#pragma unroll
      for (int r = 0; r < 16; ++r) {
        int moff = (r & 3) + 8 * (r >> 2) + 4 * h;
        int head = (out0 + moff) >> 4;
        int d = moff & 15;
        ws[VOFF + (size_t)(b * 8 + head) * 16384 + (size_t)d * 1024 + pp] =
            f2bf(a[r]);
      }
    }
  }
}

// ---------------------------------------------------------------------------
// attn: grid = bn*8+qc (512), block = 256 (4 waves), 32 q/wave, 32 x-blocks.
// No LDS, no barriers, direct stores. 3-stage pipeline (see header).
// ---------------------------------------------------------------------------
__global__ __launch_bounds__(256) void attn_kernel(
    const unsigned short* __restrict__ ws, float* __restrict__ out) {
  int bid = blockIdx.x;
  int qc = bid & 7, bn = bid >> 3;
  const unsigned short* Qg = ws + QOFF + (size_t)bn * 16384;
  const unsigned short* Kg = ws + KOFF + (size_t)bn * 16384;
  const unsigned short* Vg = ws + VOFF + (size_t)bn * 16384;

  int t = threadIdx.x;
  int wave = t >> 6, lane = t & 63;
  int h = lane >> 5, c = lane & 31;
  int q0 = qc * 128 + wave * 32;

  // Q B-frag: B[k=d=8h+j][n=q=c], K=16 exact
  bf16x8 qb = __builtin_bit_cast(
      bf16x8, *(const uint4*)(Qg + (size_t)(q0 + c) * 16 + h * 8));

  // K A-frag: lane reads K[x*32 + c][8h..8h+7]  (coalesced 16B/lane)
  const unsigned short* kbase = Kg + (size_t)c * 16 + h * 8;
  // V A-frag: lane reads V'[c&15][x*32 + 8h..]
  const unsigned short* vbase = Vg + (size_t)(c & 15) * 1024 + h * 8;

  float acc[8];
#pragma unroll
  for (int r = 0; r < 8; ++r) acc[r] = 0.f;

  // ---- prologue ----
  // V slots: va_p = frags for x-1 ; v_c = raw V(x) ; v_n = raw V(x+1)
  bf16x8 va0_p = __builtin_bit_cast(bf16x8, *(const uint4*)(vbase));
  bf16x8 va1_p = __builtin_bit_cast(bf16x8, *(const uint4*)(vbase + 16));
  uint4 v0_c = *(const uint4*)(vbase + 32);        // V(1)
  uint4 v1_c = *(const uint4*)(vbase + 48);
  uint4 v0_n = *(const uint4*)(vbase + 64);        // V(2)
  uint4 v1_n = *(const uint4*)(vbase + 80);

  // S(0) -> stage2(0) now (prologue)
  f32x16 sv_cur;
  {
    uint4 kf0 = *(const uint4*)(kbase);
    f32x16 sv0 = __builtin_amdgcn_mfma_f32_32x32x16_bf16(
        __builtin_bit_cast(bf16x8, kf0), qb, zero16(), 0, 0, 0);
    uint4 kf1 = *(const uint4*)(kbase + 512);
    sv_cur = __builtin_amdgcn_mfma_f32_32x32x16_bf16(   // S(1)
        __builtin_bit_cast(bf16x8, kf1), qb, zero16(), 0, 0, 0);
    // fall through to stage2(0) below using sv0
    float e0[16];
#pragma unroll
    for (int r = 0; r < 16; ++r) e0[r] = fexp2(sv0[r]);
    float s0 = (e0[0] + e0[1]) + (e0[2] + e0[3]);
    float s1 = (e0[4] + e0[5]) + (e0[6] + e0[7]);
    float s2 = (e0[8] + e0[9]) + (e0[10] + e0[11]);
    float s3 = (e0[12] + e0[13]) + (e0[14] + e0[15]);
    float sum = (s0 + s1) + (s2 + s3);
    sum += __shfl_xor(sum, 32);
    float rs0 = __builtin_amdgcn_rcpf(sum);
    // seed e_prev/rs_prev with x=0 values
    float e_prev[16];
#pragma unroll
    for (int r = 0; r < 16; ++r) e_prev[r] = e0[r];
    float rs_prev = rs0;

    uint4 kf_a = *(const uint4*)(kbase + 2 * 512);   // K(2)
    uint4 kf_b = *(const uint4*)(kbase + 3 * 512);   // K(3)

    // ---- main loop: x = 1..31 ----
#pragma unroll 2
    for (int x = 1; x < 32; ++x) {
      // stage1: issue S(x+1) (kf_a = K(x+1)); redundant clamp at x=31
      f32x16 sv_next = __builtin_amdgcn_mfma_f32_32x32x16_bf16(
          __builtin_bit_cast(bf16x8, kf_a), qb, zero16(), 0, 0, 0);
      kf_a = kf_b;
      int x3 = (x > 28) ? 31 : (x + 3);
      kf_b = *(const uint4*)(kbase + (size_t)x3 * 512);

      // stage3 for x-1: pack e_prev -> PV (two independent C=0 tiles) -> fold
      uint32_t pk[8];
#pragma unroll
      for (int j = 0; j < 8; ++j) pk[j] = pktrunc(e_prev[2 * j], e_prev[2 * j + 1]);
      bf16x8 p0 = __builtin_bit_cast(bf16x8, make_uint4(pk[0], pk[1], pk[2], pk[3]));
      bf16x8 p1 = __builtin_bit_cast(bf16x8, make_uint4(pk[4], pk[5], pk[6], pk[7]));
      f32x16 pv0 = __builtin_amdgcn_mfma_f32_32x32x16_bf16(va0_p, p0, zero16(), 0, 0, 0);
      f32x16 pv1 = __builtin_amdgcn_mfma_f32_32x32x16_bf16(va1_p, p1, zero16(), 0, 0, 0);
#pragma unroll
      for (int r = 0; r < 8; ++r) acc[r] = fmaf(rs_prev, pv0[r] + pv1[r], acc[r]);

      // stage2 for x: exp/sum/rcp on sv_cur (computed at iter x-1)
      float e_cur[16];
#pragma unroll
      for (int r = 0; r < 16; ++r) e_cur[r] = fexp2(sv_cur[r]);
      float t0 = (e_cur[0] + e_cur[1]) + (e_cur[2] + e_cur[3]);
      float t1 = (e_cur[4] + e_cur[5]) + (e_cur[6] + e_cur[7]);
      float t2 = (e_cur[8] + e_cur[9]) + (e_cur[10] + e_cur[11]);
      float t3 = (e_cur[12] + e_cur[13]) + (e_cur[14] + e_cur[15]);
      float su = (t0 + t1) + (t2 + t3);
      su += __shfl_xor(su, 32);
      float rs_cur = __builtin_amdgcn_rcpf(su);

      // rotate V: va_p <- V(x); v_c <- V(x+1); load V(x+2) into v_n
      va0_p = __builtin_bit_cast(bf16x8, v0_c);
      va1_p = __builtin_bit_cast(bf16x8, v1_c);
      v0_c = v0_n; v1_c = v1_n;
      int x2 = (x > 29) ? 31 : (x + 2);
      v0_n = *(const uint4*)(vbase + x2 * 32);
      v1_n = *(const uint4*)(vbase + x2 * 32 + 16);

      // rotate pipeline state
      sv_cur = sv_next;
#pragma unroll
      for (int r = 0; r < 16; ++r) e_prev[r] = e_cur[r];
      rs_prev = rs_cur;
    }

    // ---- epilogue: stage3 for x=31 ----
    uint32_t pk[8];
#pragma unroll
    for (int j = 0; j < 8; ++j) pk[j] = pktrunc(e_prev[2 * j], e_prev[2 * j + 1]);
    bf16x8 p0 = __builtin_bit_cast(bf16x8, make_uint4(pk[0], pk[1], pk[2], pk[3]));
    bf16x8 p1 = __builtin_bit_cast(bf16x8, make_uint4(pk[4], pk[5], pk[6], pk[7]));
    f32x16 pv0 = __builtin_amdgcn_mfma_f32_32x32x16_bf16(va0_p, p0, zero16(), 0, 0, 0);
    f32x16 pv1 = __builtin_amdgcn_mfma_f32_32x32x16_bf16(va1_p, p1, zero16(), 0, 0, 0);
#pragma unroll
    for (int r = 0; r < 8; ++r) acc[r] = fmaf(rs_prev, pv0[r] + pv1[r], acc[r]);
  }

  // Epilogue: D rows 0..15 valid (rows 16..31 are duplicate-V garbage)
#pragma unroll
  for (int r = 0; r < 8; ++r) {
    int d = (r & 3) + 8 * (r >> 2) + 4 * h;
    out[(size_t)(bn * 16 + d) * 1024 + q0 + c] = acc[r];
  }
}

// ---------------------------------------------------------------------------
extern "C" void kernel_launch(void* const* d_in, const int* in_sizes, int n_in,
                              void* d_out, int out_size, void* d_ws, size_t ws_size,
                              hipStream_t stream) {
  const float* x  = (const float*)d_in[0];
  const float* wq = (const float*)d_in[1];
  const float* wk = (const float*)d_in[2];
  const float* wv = (const float*)d_in[3];
  unsigned short* ws = (unsigned short*)d_ws;
  float* out = (float*)d_out;

  proj_kernel<<<dim3(384), dim3(256), 0, stream>>>(x, wq, wk, wv, ws);
  attn_kernel<<<dim3(512), dim3(256), 0, stream>>>(ws, out);
}